// Round 1
// baseline (2495.749 us; speedup 1.0000x reference)
//
#include <hip/hip_runtime.h>

// ---------------- problem constants ----------------
constexpr int NY = 100, NX = 200;     // interior grid
constexpr int PML = 35, HALF = 4;
constexpr int NYP = NY + 2 * PML;     // 170 padded rows
constexpr int NXP = NX + 2 * PML;     // 270 padded cols
constexpr int S = 2, NSRC = 1, NREC = 100, NT = 300;
constexpr float DX = 10.0f, DT = 1e-3f;
constexpr float DT2 = DT * DT;

constexpr int GRID_CELLS = NYP * NXP;       // 45900 (per shot)
constexpr int CELLS = S * GRID_CELLS;       // 91800
constexpr int CELL_BLOCKS = (CELLS + 255) / 256;   // 359

// 8th-order stencil coefficients, offsets -4..4, pre-scaled
__device__ __constant__ float C2D[9] = {
    (float)(-1.0/560.0/100.0), (float)(8.0/315.0/100.0), (float)(-1.0/5.0/100.0),
    (float)(8.0/5.0/100.0),    (float)(-205.0/72.0/100.0), (float)(8.0/5.0/100.0),
    (float)(-1.0/5.0/100.0),   (float)(8.0/315.0/100.0),  (float)(-1.0/560.0/100.0)};
__device__ __constant__ float C1D[9] = {
    (float)(1.0/280.0/10.0), (float)(-4.0/105.0/10.0), (float)(1.0/5.0/10.0),
    (float)(-4.0/5.0/10.0),  0.0f,                     (float)(4.0/5.0/10.0),
    (float)(-1.0/5.0/10.0),  (float)(4.0/105.0/10.0),  (float)(-1.0/280.0/10.0)};

// ---------------- setup kernels ----------------
__global__ void vmax_kernel(const float* __restrict__ vp, float* __restrict__ cst) {
    __shared__ float red[256];
    float m = 0.0f;
    for (int i = threadIdx.x; i < NY * NX; i += 256) m = fmaxf(m, vp[i]);
    red[threadIdx.x] = m;
    __syncthreads();
    for (int s2 = 128; s2 > 0; s2 >>= 1) {
        if (threadIdx.x < s2) red[threadIdx.x] = fmaxf(red[threadIdx.x], red[threadIdx.x + s2]);
        __syncthreads();
    }
    if (threadIdx.x == 0)
        cst[0] = 3.0f * red[0] * logf(1000.0f) / (2.0f * PML * DX);  // sigma_max
}

__device__ __forceinline__ float sigma_of(int d, int n, float smax) {
    float r = fmaxf(fmaxf((float)(PML - d) / (float)PML,
                          (float)(d - (n - 1 - PML)) / (float)PML), 0.0f);
    return smax * r * r;
}

__global__ void setup_kernel(const float* __restrict__ vp, const float* __restrict__ cst,
                             float* __restrict__ A, float* __restrict__ Bc,
                             float* __restrict__ Dinv, float* __restrict__ E,
                             float* __restrict__ by, float* __restrict__ bym1,
                             float* __restrict__ bx, float* __restrict__ bxm1) {
    int idx = blockIdx.x * 256 + threadIdx.x;
    float smax = cst[0];
    if (idx < GRID_CELLS) {
        int y = idx / NXP, x = idx - (idx / NXP) * NXP;
        int vy = min(max(y - PML, 0), NY - 1);
        int vx = min(max(x - PML, 0), NX - 1);
        float v = vp[vy * NX + vx];
        float syv = sigma_of(y, NYP, smax);
        float sxv = sigma_of(x, NXP, smax);
        float s_ = syv + sxv;
        float pr = syv * sxv;
        A[idx] = 2.0f - pr * DT2;
        Bc[idx] = 1.0f - 0.5f * s_ * DT;
        Dinv[idx] = 1.0f / (1.0f + 0.5f * s_ * DT);
        E[idx] = DT2 * v * v;
    }
    if (idx < NYP) {
        float s0 = sigma_of(idx, NYP, smax);
        float b = expf(-s0 * DT);
        by[idx] = b; bym1[idx] = b - 1.0f;
    }
    if (idx < NXP) {
        float s0 = sigma_of(idx, NXP, smax);
        float b = expf(-s0 * DT);
        bx[idx] = b; bxm1[idx] = b - 1.0f;
    }
}

// ---------------- per-step kernel ----------------
__device__ __forceinline__ float ldp(const float* __restrict__ p, int s, int y, int x) {
    return (y >= 0 && y < NYP && x >= 0 && x < NXP) ? p[(s * NYP + y) * NXP + x] : 0.0f;
}

__global__ __launch_bounds__(256) void step_kernel(
    const float* __restrict__ u, const float* __restrict__ um, float* __restrict__ un,
    const float* __restrict__ pyO, float* __restrict__ pyN,
    const float* __restrict__ pxO, float* __restrict__ pxN,
    const float* __restrict__ A, const float* __restrict__ Bc,
    const float* __restrict__ Dinv, const float* __restrict__ E,
    const float* __restrict__ by, const float* __restrict__ bym1,
    const float* __restrict__ bx, const float* __restrict__ bxm1,
    const int* __restrict__ src_loc, const int* __restrict__ rec_loc,
    const float* __restrict__ src, float* __restrict__ out, int t) {

    int s, y, x;
    bool is_rec = false;
    int out_idx = 0;
    if (blockIdx.x < CELL_BLOCKS) {
        int gid = blockIdx.x * 256 + threadIdx.x;
        if (gid >= CELLS) return;
        s = gid / GRID_CELLS;
        int rem = gid - s * GRID_CELLS;
        y = rem / NXP;
        x = rem - y * NXP;
    } else {
        int idx = threadIdx.x;
        if (idx >= S * NREC) return;
        s = idx / NREC;
        int r = idx - s * NREC;
        y = rec_loc[(s * NREC + r) * 2 + 0] + PML;
        x = rec_loc[(s * NREC + r) * 2 + 1] + PML;
        is_rec = true;
        out_idx = (s * NT + t) * NREC + r;
    }

    const int base = (s * NYP + y) * NXP + x;
    const int gidx = y * NXP + x;

    // u column y-8..y+8 and row x-8..x+8
    float ucol[17], urow[17];
#pragma unroll
    for (int i = 0; i < 17; i++) ucol[i] = ldp(u, s, y - 8 + i, x);
#pragma unroll
    for (int i = 0; i < 17; i++) urow[i] = (i == 8) ? ucol[8] : ldp(u, s, y, x - 8 + i);

    // redundantly recompute updated py for rows y-4..y+4 (this column)
    float pyn[9];
#pragma unroll
    for (int r = 0; r < 9; r++) {
        int yy = y - 4 + r;
        float d1 = 0.0f;
#pragma unroll
        for (int k = 0; k < 9; k++)
            if (k != 4) d1 = fmaf(C1D[k], ucol[r + k], d1);
        bool in = (yy >= 0 && yy < NYP);
        float bv = in ? by[yy] : 0.0f;
        float bm = in ? bym1[yy] : 0.0f;
        pyn[r] = fmaf(bv, ldp(pyO, s, yy, x), bm * d1);
    }
    // redundantly recompute updated px for cols x-4..x+4 (this row)
    float pxn[9];
#pragma unroll
    for (int r = 0; r < 9; r++) {
        int xx = x - 4 + r;
        float d1 = 0.0f;
#pragma unroll
        for (int k = 0; k < 9; k++)
            if (k != 4) d1 = fmaf(C1D[k], urow[r + k], d1);
        bool in = (xx >= 0 && xx < NXP);
        float bv = in ? bx[xx] : 0.0f;
        float bm = in ? bxm1[xx] : 0.0f;
        pxn[r] = fmaf(bv, ldp(pxO, s, y, xx), bm * d1);
    }

    float d2y = 0.0f, d2x = 0.0f, d1py = 0.0f, d1px = 0.0f;
#pragma unroll
    for (int k = 0; k < 9; k++) {
        d2y = fmaf(C2D[k], ucol[4 + k], d2y);
        d2x = fmaf(C2D[k], urow[4 + k], d2x);
        if (k != 4) {
            d1py = fmaf(C1D[k], pyn[k], d1py);
            d1px = fmaf(C1D[k], pxn[k], d1px);
        }
    }
    float lap = d2y + d2x + d1py + d1px;

    // source injection
    float f = 0.0f;
#pragma unroll
    for (int j = 0; j < NSRC; j++) {
        int sy_ = src_loc[(s * NSRC + j) * 2 + 0] + PML;
        int sx_ = src_loc[(s * NSRC + j) * 2 + 1] + PML;
        if (y == sy_ && x == sx_) f += src[(s * NSRC + j) * NT + t];
    }

    float unv = (A[gidx] * ucol[8] - Bc[gidx] * um[base] + E[gidx] * (lap + f)) * Dinv[gidx];

    if (is_rec) {
        out[out_idx] = unv;
    } else {
        un[base] = unv;
        pyN[base] = pyn[4];
        pxN[base] = pxn[4];
    }
}

// ---------------- host launch ----------------
extern "C" void kernel_launch(void* const* d_in, const int* in_sizes, int n_in,
                              void* d_out, int out_size, void* d_ws, size_t ws_size,
                              hipStream_t stream) {
    const float* vp = (const float*)d_in[0];
    const float* src = (const float*)d_in[1];
    const int* src_loc = (const int*)d_in[2];
    const int* rec_loc = (const int*)d_in[3];
    float* out = (float*)d_out;

    float* ws = (float*)d_ws;
    float* U[3]  = {ws, ws + CELLS, ws + 2 * CELLS};
    float* PY[2] = {ws + 3 * CELLS, ws + 4 * CELLS};
    float* PX[2] = {ws + 5 * CELLS, ws + 6 * CELLS};
    float* A    = ws + 7 * CELLS;
    float* Bc   = A + GRID_CELLS;
    float* Dinv = Bc + GRID_CELLS;
    float* E    = Dinv + GRID_CELLS;
    float* by   = E + GRID_CELLS;
    float* bym1 = by + NYP;
    float* bx   = bym1 + NYP;
    float* bxm1 = bx + NXP;
    float* cst  = bxm1 + NXP;

    // zero state (u/um/un, py, px ping-pong buffers)
    hipMemsetAsync(d_ws, 0, (size_t)(7 * CELLS) * sizeof(float), stream);
    vmax_kernel<<<1, 256, 0, stream>>>(vp, cst);
    setup_kernel<<<(GRID_CELLS + 255) / 256, 256, 0, stream>>>(
        vp, cst, A, Bc, Dinv, E, by, bym1, bx, bxm1);

    for (int t = 0; t < NT; t++) {
        step_kernel<<<CELL_BLOCKS + 1, 256, 0, stream>>>(
            U[(t + 1) % 3], U[t % 3], U[(t + 2) % 3],
            PY[t % 2], PY[(t + 1) % 2],
            PX[t % 2], PX[(t + 1) % 2],
            A, Bc, Dinv, E, by, bym1, bx, bxm1,
            src_loc, rec_loc, src, out, t);
    }
}